// Round 4
// baseline (340.029 us; speedup 1.0000x reference)
//
#include <hip/hip_runtime.h>
#include <math.h>

namespace {
constexpr int kB  = 64;
constexpr int kT  = 1024;
constexpr int kK  = 512;
constexpr int kC  = 16;          // chunks along T per block (T-parallelism)
constexpr int kL  = kT / kC;     // 64 steps per chunk
constexpr int kKB = 32;          // k-columns per block (128 B coalescing)
constexpr int kBlockThreads = kKB * kC;   // 512
constexpr int kR  = 16;          // prefetch ring depth
constexpr float kDT = 0.001f;
}

// Chunked linear scan, v3: NO per-thread output array (v1/v2's r[] was
// silently placed in AGPRs -> load->waitcnt->accvgpr_write serialization;
// 85% of time was s_waitcnt stalls at both 28% and 57% occupancy).
// Phase 1 streams the chunk keeping only the 2-float end state; phase 3
// RE-SCANS the chunk from the true entry state, re-reading u (second read
// is L2/L3-hot: per-block footprint 128 KB, total = input 128 MB < 256 MB
// L3). Phase 3 is exactly the reference recurrence, so no decomposition
// error beyond entry states. ~40 VGPRs -> 4 blocks/CU = 32 waves/CU, with
// blocks phase-staggered so HBM reads/writes overlap.
__global__ __launch_bounds__(kBlockThreads, 8) void alpha_rescan(
    const float* __restrict__ in,
    const float* __restrict__ init_level,
    const float* __restrict__ tau,
    float* __restrict__ out)
{
    __shared__ float sx0[kC][kKB];
    __shared__ float sx1[kC][kKB];

    const int tid = threadIdx.x;
    const int kl  = tid & (kKB - 1);     // k within block (fast -> coalesced)
    const int c   = tid >> 5;            // chunk index 0..15
    const int bx  = blockIdx.x;
    const int b   = bx >> 4;             // / (kK/kKB = 16)
    const int k   = ((bx & 15) << 5) + kl;

    // Per-feature coefficients (identical arithmetic to the reference).
    const float tc      = fmaxf(tau[k], 1e-8f);
    const float dt_tau  = kDT / tc;
    const float dt_tau2 = dt_tau / tc;
    const float e       = expf(-dt_tau);

    const float a00 = e * (1.0f - dt_tau);
    const float a01 = e * (-dt_tau2);
    const float a10 = e * kDT;
    const float a11 = e * (1.0f + dt_tau);
    const float b0  = e * dt_tau2;
    const float b1  = 1.0f - e * (1.0f + dt_tau);

    const float il = init_level[k];

    const size_t base = (size_t)b * kT * kK + (size_t)c * kL * kK + k;
    const float* __restrict__ pin = in + base;

    // ---- Phase 1: stream chunk, compute end state only. Ring depth 16. ----
    float buf[kR];
    #pragma unroll
    for (int i = 0; i < kR; ++i) buf[i] = pin[(size_t)i * kK];

    float x0 = 0.0f, x1 = 0.0f;
    #pragma unroll
    for (int tb = 0; tb < kL - kR; tb += kR) {
        const float* __restrict__ pld = pin + (size_t)(tb + kR) * kK;
        #pragma unroll
        for (int i = 0; i < kR; ++i) {
            const float u = buf[i];
            buf[i] = pld[(size_t)i * kK];
            const float nx0 = fmaf(a00, x0, fmaf(a01, x1, b0 * u));
            const float nx1 = fmaf(a10, x0, fmaf(a11, x1, b1 * u));
            x0 = nx0; x1 = nx1;
        }
    }
    #pragma unroll
    for (int i = 0; i < kR; ++i) {
        const float u = buf[i];
        const float nx0 = fmaf(a00, x0, fmaf(a01, x1, b0 * u));
        const float nx1 = fmaf(a10, x0, fmaf(a11, x1, b1 * u));
        x0 = nx0; x1 = nx1;
    }

    sx0[c][kl] = x0;
    sx1[c][kl] = x1;
    __syncthreads();

    // ---- Phase 2: A^64 via 6 squarings; serial prefix over predecessors. ----
    float m00 = a00, m01 = a01, m10 = a10, m11 = a11;
    #pragma unroll
    for (int s = 0; s < 6; ++s) {
        const float t00 = fmaf(m00, m00, m01 * m10);
        const float t01 = fmaf(m00, m01, m01 * m11);
        const float t10 = fmaf(m10, m00, m11 * m10);
        const float t11 = fmaf(m10, m01, m11 * m11);
        m00 = t00; m01 = t01; m10 = t10; m11 = t11;
    }

    float v0 = 0.0f, v1 = il;            // state at t = -1
    for (int j = 0; j < c; ++j) {
        const float p0 = fmaf(m00, v0, m01 * v1) + sx0[j][kl];
        const float p1 = fmaf(m10, v0, m11 * v1) + sx1[j][kl];
        v0 = p0; v1 = p1;
    }
    // (v0,v1) = true state at end of chunk c-1 (entry state for chunk c).

    // ---- Phase 3: full re-scan from true entry state (L2/L3-hot reads),
    //      store outputs. This IS the reference recurrence. ----
    float* __restrict__ pout = out + base;
    #pragma unroll
    for (int i = 0; i < kR; ++i) buf[i] = pin[(size_t)i * kK];

    #pragma unroll
    for (int tb = 0; tb < kL - kR; tb += kR) {
        const float* __restrict__ pld = pin  + (size_t)(tb + kR) * kK;
        float* __restrict__ pst       = pout + (size_t)tb * kK;
        #pragma unroll
        for (int i = 0; i < kR; ++i) {
            const float u = buf[i];
            buf[i] = pld[(size_t)i * kK];
            const float n0 = fmaf(a00, v0, fmaf(a01, v1, b0 * u));
            const float n1 = fmaf(a10, v0, fmaf(a11, v1, b1 * u));
            v0 = n0; v1 = n1;
            pst[(size_t)i * kK] = n1;
        }
    }
    {
        float* __restrict__ pst = pout + (size_t)(kL - kR) * kK;
        #pragma unroll
        for (int i = 0; i < kR; ++i) {
            const float u = buf[i];
            const float n0 = fmaf(a00, v0, fmaf(a01, v1, b0 * u));
            const float n1 = fmaf(a10, v0, fmaf(a11, v1, b1 * u));
            v0 = n0; v1 = n1;
            pst[(size_t)i * kK] = n1;
        }
    }
}

extern "C" void kernel_launch(void* const* d_in, const int* in_sizes, int n_in,
                              void* d_out, int out_size, void* d_ws, size_t ws_size,
                              hipStream_t stream) {
    const float* in  = (const float*)d_in[0];   // [64,1024,512] fp32
    const float* il  = (const float*)d_in[1];   // [512] fp32
    const float* tau = (const float*)d_in[2];   // [512] fp32
    float* out = (float*)d_out;                 // [64,1024,512] fp32

    dim3 block(kBlockThreads);                        // 512
    dim3 grid(kB * (kK / kKB));                       // 64 * 16 = 1024 blocks
    alpha_rescan<<<grid, block, 0, stream>>>(in, il, tau, out);
}

// Round 5
// 264.290 us; speedup vs baseline: 1.2866x; 1.2866x over previous
//
#include <hip/hip_runtime.h>
#include <math.h>

namespace {
constexpr int kB = 64, kT = 1024, kK = 512;
constexpr int kC = 32;               // chunks along T
constexpr int kL = kT / kC;          // 32 steps per chunk
constexpr int kTh = 256;             // threads per block
constexpr int kChains = kB * kK * kC;        // 1,048,576 (b,k,c) triples
constexpr float kDT = 0.001f;
}

// Shared per-feature coefficient computation (identical to reference math).
__device__ __forceinline__ void alpha_coeffs(float tk,
    float& a00, float& a01, float& a10, float& a11, float& b0, float& b1)
{
    const float tc      = fmaxf(tk, 1e-8f);
    const float dt_tau  = kDT / tc;
    const float dt_tau2 = dt_tau / tc;
    const float e       = expf(-dt_tau);
    a00 = e * (1.0f - dt_tau);
    a01 = e * (-dt_tau2);
    a10 = e * kDT;
    a11 = e * (1.0f + dt_tau);
    b0  = e * dt_tau2;
    b1  = 1.0f - e * (1.0f + dt_tau);
}

// ---------------- k1: per-chunk local end-states (pure read stream) --------
// thread g = (c*kB + b)*kK + k. Reads 32 inputs (ring-8), writes S[g].
__global__ __launch_bounds__(kTh, 8) void alpha_k1_states(
    const float* __restrict__ in,
    const float* __restrict__ tau,
    float2* __restrict__ S)
{
    const int g  = blockIdx.x * kTh + threadIdx.x;
    const int k  = g & (kK - 1);
    const int bc = g >> 9;               // c*kB + b
    const int b  = bc & (kB - 1);
    const int c  = bc >> 6;

    float a00, a01, a10, a11, b0, b1;
    alpha_coeffs(tau[k], a00, a01, a10, a11, b0, b1);

    const float* __restrict__ pin =
        in + (size_t)b * kT * kK + (size_t)c * kL * kK + k;

    float buf[8];
    #pragma unroll
    for (int i = 0; i < 8; ++i) buf[i] = pin[(size_t)i * kK];

    float x0 = 0.0f, x1 = 0.0f;
    #pragma unroll
    for (int tb = 0; tb < kL - 8; tb += 8) {
        const float* __restrict__ pld = pin + (size_t)(tb + 8) * kK;
        #pragma unroll
        for (int i = 0; i < 8; ++i) {
            const float u = buf[i];
            buf[i] = pld[(size_t)i * kK];
            const float nx0 = fmaf(a00, x0, fmaf(a01, x1, b0 * u));
            const float nx1 = fmaf(a10, x0, fmaf(a11, x1, b1 * u));
            x0 = nx0; x1 = nx1;
        }
    }
    #pragma unroll
    for (int i = 0; i < 8; ++i) {
        const float u = buf[i];
        const float nx0 = fmaf(a00, x0, fmaf(a01, x1, b0 * u));
        const float nx1 = fmaf(a10, x0, fmaf(a11, x1, b1 * u));
        x0 = nx0; x1 = nx1;
    }

    S[g] = make_float2(x0, x1);
}

// ---------------- k2: serial prefix over chunks, S -> entry states --------
// thread h = b*kK + k. In-place: slot c read (S_c), then overwritten with
// X_c = entry state of chunk c. X_0 = (0, init_level); X_{c+1} = A^32 X_c + S_c.
__global__ __launch_bounds__(kTh, 8) void alpha_k2_prefix(
    const float* __restrict__ init_level,
    const float* __restrict__ tau,
    float2* __restrict__ S)
{
    const int h = blockIdx.x * kTh + threadIdx.x;    // 0..32767
    const int k = h & (kK - 1);

    float a00, a01, a10, a11, b0, b1;
    alpha_coeffs(tau[k], a00, a01, a10, a11, b0, b1);

    // A^32 via 5 squarings.
    float m00 = a00, m01 = a01, m10 = a10, m11 = a11;
    #pragma unroll
    for (int s = 0; s < 5; ++s) {
        const float t00 = fmaf(m00, m00, m01 * m10);
        const float t01 = fmaf(m00, m01, m01 * m11);
        const float t10 = fmaf(m10, m00, m11 * m10);
        const float t11 = fmaf(m10, m01, m11 * m11);
        m00 = t00; m01 = t01; m10 = t10; m11 = t11;
    }

    float2* __restrict__ pS = S + h;                 // stride kB*kK per chunk
    float v0 = 0.0f, v1 = init_level[k];
    #pragma unroll
    for (int c = 0; c < kC; ++c) {
        const float2 s = pS[(size_t)c * kB * kK];    // S_c (read first)
        pS[(size_t)c * kB * kK] = make_float2(v0, v1); // X_c (entry state)
        const float p0 = fmaf(m00, v0, m01 * v1) + s.x;
        const float p1 = fmaf(m10, v0, m11 * v1) + s.y;
        v0 = p0; v1 = p1;
    }
}

// ---------------- k3: rescan from entry state, store (write stream) -------
// Input re-read is L3-hot: k1 streamed it, and only 16 MB moved since.
__global__ __launch_bounds__(kTh, 8) void alpha_k3_rescan(
    const float* __restrict__ in,
    const float* __restrict__ tau,
    const float2* __restrict__ X,
    float* __restrict__ out)
{
    const int g  = blockIdx.x * kTh + threadIdx.x;
    const int k  = g & (kK - 1);
    const int bc = g >> 9;
    const int b  = bc & (kB - 1);
    const int c  = bc >> 6;

    float a00, a01, a10, a11, b0, b1;
    alpha_coeffs(tau[k], a00, a01, a10, a11, b0, b1);

    const float2 x = X[g];
    float v0 = x.x, v1 = x.y;

    const size_t base = (size_t)b * kT * kK + (size_t)c * kL * kK + k;
    const float* __restrict__ pin  = in  + base;
    float* __restrict__ pout       = out + base;

    float buf[8];
    #pragma unroll
    for (int i = 0; i < 8; ++i) buf[i] = pin[(size_t)i * kK];

    #pragma unroll
    for (int tb = 0; tb < kL - 8; tb += 8) {
        const float* __restrict__ pld = pin  + (size_t)(tb + 8) * kK;
        float* __restrict__ pst       = pout + (size_t)tb * kK;
        #pragma unroll
        for (int i = 0; i < 8; ++i) {
            const float u = buf[i];
            buf[i] = pld[(size_t)i * kK];
            const float n0 = fmaf(a00, v0, fmaf(a01, v1, b0 * u));
            const float n1 = fmaf(a10, v0, fmaf(a11, v1, b1 * u));
            v0 = n0; v1 = n1;
            pst[(size_t)i * kK] = n1;
        }
    }
    {
        float* __restrict__ pst = pout + (size_t)(kL - 8) * kK;
        #pragma unroll
        for (int i = 0; i < 8; ++i) {
            const float u = buf[i];
            const float n0 = fmaf(a00, v0, fmaf(a01, v1, b0 * u));
            const float n1 = fmaf(a10, v0, fmaf(a11, v1, b1 * u));
            v0 = n0; v1 = n1;
            pst[(size_t)i * kK] = n1;
        }
    }
}

// ---------------- fallback: verified single-kernel v2 (ws too small) ------
__global__ __launch_bounds__(1024, 8) void alpha_scan_c32(
    const float* __restrict__ in,
    const float* __restrict__ init_level,
    const float* __restrict__ tau,
    float* __restrict__ out)
{
    __shared__ float sx0[32][32];
    __shared__ float sx1[32][32];

    const int tid = threadIdx.x;
    const int kl  = tid & 31;
    const int c   = tid >> 5;
    const int bx  = blockIdx.x;
    const int b   = bx >> 4;
    const int k   = ((bx & 15) << 5) + kl;

    float a00, a01, a10, a11, b0, b1;
    alpha_coeffs(tau[k], a00, a01, a10, a11, b0, b1);
    const float il = init_level[k];

    const size_t base = (size_t)b * kT * kK + (size_t)c * 32 * kK + k;
    const float* __restrict__ pin = in + base;

    float r[32];
    #pragma unroll
    for (int i = 0; i < 32; ++i) r[i] = pin[(size_t)i * kK];

    float x0 = 0.0f, x1 = 0.0f;
    #pragma unroll
    for (int i = 0; i < 32; ++i) {
        const float u   = r[i];
        const float nx0 = fmaf(a00, x0, fmaf(a01, x1, b0 * u));
        const float nx1 = fmaf(a10, x0, fmaf(a11, x1, b1 * u));
        x0 = nx0; x1 = nx1;
        r[i] = nx1;
    }
    sx0[c][kl] = x0;
    sx1[c][kl] = x1;
    __syncthreads();

    float m00 = a00, m01 = a01, m10 = a10, m11 = a11;
    #pragma unroll
    for (int s = 0; s < 5; ++s) {
        const float t00 = fmaf(m00, m00, m01 * m10);
        const float t01 = fmaf(m00, m01, m01 * m11);
        const float t10 = fmaf(m10, m00, m11 * m10);
        const float t11 = fmaf(m10, m01, m11 * m11);
        m00 = t00; m01 = t01; m10 = t10; m11 = t11;
    }
    float v0 = 0.0f, v1 = il;
    for (int j = 0; j < c; ++j) {
        const float p0 = fmaf(m00, v0, m01 * v1) + sx0[j][kl];
        const float p1 = fmaf(m10, v0, m11 * v1) + sx1[j][kl];
        v0 = p0; v1 = p1;
    }
    float* __restrict__ pout = out + base;
    #pragma unroll
    for (int i = 0; i < 32; ++i) {
        const float n0 = fmaf(a00, v0, a01 * v1);
        const float n1 = fmaf(a10, v0, a11 * v1);
        v0 = n0; v1 = n1;
        pout[(size_t)i * kK] = r[i] + n1;
    }
}

extern "C" void kernel_launch(void* const* d_in, const int* in_sizes, int n_in,
                              void* d_out, int out_size, void* d_ws, size_t ws_size,
                              hipStream_t stream) {
    const float* in  = (const float*)d_in[0];   // [64,1024,512] fp32
    const float* il  = (const float*)d_in[1];   // [512] fp32
    const float* tau = (const float*)d_in[2];   // [512] fp32
    float* out = (float*)d_out;                 // [64,1024,512] fp32

    const size_t ws_needed = (size_t)kChains * sizeof(float2);   // 8 MiB
    if (d_ws != nullptr && ws_size >= ws_needed) {
        float2* S = (float2*)d_ws;
        dim3 blk(kTh);
        alpha_k1_states<<<dim3(kChains / kTh), blk, 0, stream>>>(in, tau, S);
        alpha_k2_prefix<<<dim3((kB * kK) / kTh), blk, 0, stream>>>(il, tau, S);
        alpha_k3_rescan<<<dim3(kChains / kTh), blk, 0, stream>>>(in, tau, S, out);
    } else {
        // Fallback: verified single-kernel chunked scan (round-3 kernel).
        alpha_scan_c32<<<dim3(kB * (kK / 32)), dim3(1024), 0, stream>>>(
            in, il, tau, out);
    }
}

// Round 6
// 253.759 us; speedup vs baseline: 1.3400x; 1.0415x over previous
//
#include <hip/hip_runtime.h>
#include <math.h>

namespace {
constexpr int kB = 64, kT = 1024, kK = 512;
constexpr int kC = 32;               // chunks along T
constexpr int kL = kT / kC;          // 32 steps per chunk
constexpr int kTh = 256;             // threads per block (k1)
constexpr int kChains = kB * kK * kC;        // 1,048,576 (b,k,c) triples
constexpr float kDT = 0.001f;
}

// Shared per-feature coefficient computation (identical to reference math).
__device__ __forceinline__ void alpha_coeffs(float tk,
    float& a00, float& a01, float& a10, float& a11, float& b0, float& b1)
{
    const float tc      = fmaxf(tk, 1e-8f);
    const float dt_tau  = kDT / tc;
    const float dt_tau2 = dt_tau / tc;
    const float e       = expf(-dt_tau);
    a00 = e * (1.0f - dt_tau);
    a01 = e * (-dt_tau2);
    a10 = e * kDT;
    a11 = e * (1.0f + dt_tau);
    b0  = e * dt_tau2;
    b1  = 1.0f - e * (1.0f + dt_tau);
}

// ---------------- k1: per-chunk local end-states (pure read stream) --------
// thread g = (c*kB + b)*kK + k. Reads 32 inputs (ring-8), writes S[g].
// Normal (caching) loads: this pass deliberately stages the input in L3
// for kernel 2's re-read. S (8 MB) stored normally (re-read by k2 soon).
__global__ __launch_bounds__(kTh, 8) void alpha_k1_states(
    const float* __restrict__ in,
    const float* __restrict__ tau,
    float2* __restrict__ S)
{
    const int g  = blockIdx.x * kTh + threadIdx.x;
    const int k  = g & (kK - 1);
    const int bc = g >> 9;               // c*kB + b
    const int b  = bc & (kB - 1);
    const int c  = bc >> 6;

    float a00, a01, a10, a11, b0, b1;
    alpha_coeffs(tau[k], a00, a01, a10, a11, b0, b1);

    const float* __restrict__ pin =
        in + (size_t)b * kT * kK + (size_t)c * kL * kK + k;

    float buf[8];
    #pragma unroll
    for (int i = 0; i < 8; ++i) buf[i] = pin[(size_t)i * kK];

    float x0 = 0.0f, x1 = 0.0f;
    #pragma unroll
    for (int tb = 0; tb < kL - 8; tb += 8) {
        const float* __restrict__ pld = pin + (size_t)(tb + 8) * kK;
        #pragma unroll
        for (int i = 0; i < 8; ++i) {
            const float u = buf[i];
            buf[i] = pld[(size_t)i * kK];
            const float nx0 = fmaf(a00, x0, fmaf(a01, x1, b0 * u));
            const float nx1 = fmaf(a10, x0, fmaf(a11, x1, b1 * u));
            x0 = nx0; x1 = nx1;
        }
    }
    #pragma unroll
    for (int i = 0; i < 8; ++i) {
        const float u = buf[i];
        const float nx0 = fmaf(a00, x0, fmaf(a01, x1, b0 * u));
        const float nx1 = fmaf(a10, x0, fmaf(a11, x1, b1 * u));
        x0 = nx0; x1 = nx1;
    }

    S[g] = make_float2(x0, x1);
}

// ---------------- k2: fused prefix (LDS) + rescan, NT output stores -------
// Block = 32 k-columns x 32 chunks (1024 thr) covering one (b, k-group).
// Phase A: load S from ws into LDS; phase B: A^32 (5 squarings) + serial
// prefix over predecessor chunk states -> true entry state; phase C: rescan
// the 32-step chunk from the entry state (input re-read is L3-hot from k1)
// and store via __builtin_nontemporal_store so the 131 MB output stream
// does NOT allocate in L2/L3 and cannot evict the staged input (round-4/5
// lesson: cached writes self-evicted the input, FETCH 221 MB).
__global__ __launch_bounds__(1024, 8) void alpha_k2_rescan(
    const float* __restrict__ in,
    const float* __restrict__ init_level,
    const float* __restrict__ tau,
    const float2* __restrict__ S,
    float* __restrict__ out)
{
    __shared__ float sx0[kC][32];
    __shared__ float sx1[kC][32];

    const int tid = threadIdx.x;
    const int kl  = tid & 31;            // k within block (fast -> coalesced)
    const int c   = tid >> 5;            // chunk index 0..31
    const int bx  = blockIdx.x;
    const int b   = bx >> 4;             // / (kK/32 = 16)
    const int k   = ((bx & 15) << 5) + kl;

    float a00, a01, a10, a11, b0, b1;
    alpha_coeffs(tau[k], a00, a01, a10, a11, b0, b1);
    const float il = init_level[k];

    // Phase A: chunk end-states into LDS.
    const float2 s = S[(size_t)(c * kB + b) * kK + k];
    sx0[c][kl] = s.x;
    sx1[c][kl] = s.y;
    __syncthreads();

    // Phase B: A^32 via 5 squarings, then serial prefix over j < c.
    float m00 = a00, m01 = a01, m10 = a10, m11 = a11;
    #pragma unroll
    for (int sq = 0; sq < 5; ++sq) {
        const float t00 = fmaf(m00, m00, m01 * m10);
        const float t01 = fmaf(m00, m01, m01 * m11);
        const float t10 = fmaf(m10, m00, m11 * m10);
        const float t11 = fmaf(m10, m01, m11 * m11);
        m00 = t00; m01 = t01; m10 = t10; m11 = t11;
    }
    float v0 = 0.0f, v1 = il;            // state entering chunk 0
    for (int j = 0; j < c; ++j) {
        const float p0 = fmaf(m00, v0, m01 * v1) + sx0[j][kl];
        const float p1 = fmaf(m10, v0, m11 * v1) + sx1[j][kl];
        v0 = p0; v1 = p1;
    }
    // (v0,v1) = true state entering chunk c.

    // Phase C: rescan from entry state; NT stores.
    const size_t base = (size_t)b * kT * kK + (size_t)c * kL * kK + k;
    const float* __restrict__ pin  = in  + base;
    float* __restrict__ pout       = out + base;

    float buf[8];
    #pragma unroll
    for (int i = 0; i < 8; ++i) buf[i] = pin[(size_t)i * kK];

    #pragma unroll
    for (int tb = 0; tb < kL - 8; tb += 8) {
        const float* __restrict__ pld = pin  + (size_t)(tb + 8) * kK;
        float* __restrict__ pst       = pout + (size_t)tb * kK;
        #pragma unroll
        for (int i = 0; i < 8; ++i) {
            const float u = buf[i];
            buf[i] = pld[(size_t)i * kK];
            const float n0 = fmaf(a00, v0, fmaf(a01, v1, b0 * u));
            const float n1 = fmaf(a10, v0, fmaf(a11, v1, b1 * u));
            v0 = n0; v1 = n1;
            __builtin_nontemporal_store(n1, &pst[(size_t)i * kK]);
        }
    }
    {
        float* __restrict__ pst = pout + (size_t)(kL - 8) * kK;
        #pragma unroll
        for (int i = 0; i < 8; ++i) {
            const float u = buf[i];
            const float n0 = fmaf(a00, v0, fmaf(a01, v1, b0 * u));
            const float n1 = fmaf(a10, v0, fmaf(a11, v1, b1 * u));
            v0 = n0; v1 = n1;
            __builtin_nontemporal_store(n1, &pst[(size_t)i * kK]);
        }
    }
}

// ---------------- fallback: verified single-kernel v2 (ws too small) ------
__global__ __launch_bounds__(1024, 8) void alpha_scan_c32(
    const float* __restrict__ in,
    const float* __restrict__ init_level,
    const float* __restrict__ tau,
    float* __restrict__ out)
{
    __shared__ float sx0[32][32];
    __shared__ float sx1[32][32];

    const int tid = threadIdx.x;
    const int kl  = tid & 31;
    const int c   = tid >> 5;
    const int bx  = blockIdx.x;
    const int b   = bx >> 4;
    const int k   = ((bx & 15) << 5) + kl;

    float a00, a01, a10, a11, b0, b1;
    alpha_coeffs(tau[k], a00, a01, a10, a11, b0, b1);
    const float il = init_level[k];

    const size_t base = (size_t)b * kT * kK + (size_t)c * 32 * kK + k;
    const float* __restrict__ pin = in + base;

    float r[32];
    #pragma unroll
    for (int i = 0; i < 32; ++i) r[i] = pin[(size_t)i * kK];

    float x0 = 0.0f, x1 = 0.0f;
    #pragma unroll
    for (int i = 0; i < 32; ++i) {
        const float u   = r[i];
        const float nx0 = fmaf(a00, x0, fmaf(a01, x1, b0 * u));
        const float nx1 = fmaf(a10, x0, fmaf(a11, x1, b1 * u));
        x0 = nx0; x1 = nx1;
        r[i] = nx1;
    }
    sx0[c][kl] = x0;
    sx1[c][kl] = x1;
    __syncthreads();

    float m00 = a00, m01 = a01, m10 = a10, m11 = a11;
    #pragma unroll
    for (int sq = 0; sq < 5; ++sq) {
        const float t00 = fmaf(m00, m00, m01 * m10);
        const float t01 = fmaf(m00, m01, m01 * m11);
        const float t10 = fmaf(m10, m00, m11 * m10);
        const float t11 = fmaf(m10, m01, m11 * m11);
        m00 = t00; m01 = t01; m10 = t10; m11 = t11;
    }
    float v0 = 0.0f, v1 = il;
    for (int j = 0; j < c; ++j) {
        const float p0 = fmaf(m00, v0, m01 * v1) + sx0[j][kl];
        const float p1 = fmaf(m10, v0, m11 * v1) + sx1[j][kl];
        v0 = p0; v1 = p1;
    }
    float* __restrict__ pout = out + base;
    #pragma unroll
    for (int i = 0; i < 32; ++i) {
        const float n0 = fmaf(a00, v0, a01 * v1);
        const float n1 = fmaf(a10, v0, a11 * v1);
        v0 = n0; v1 = n1;
        pout[(size_t)i * kK] = r[i] + n1;
    }
}

extern "C" void kernel_launch(void* const* d_in, const int* in_sizes, int n_in,
                              void* d_out, int out_size, void* d_ws, size_t ws_size,
                              hipStream_t stream) {
    const float* in  = (const float*)d_in[0];   // [64,1024,512] fp32
    const float* il  = (const float*)d_in[1];   // [512] fp32
    const float* tau = (const float*)d_in[2];   // [512] fp32
    float* out = (float*)d_out;                 // [64,1024,512] fp32

    const size_t ws_needed = (size_t)kChains * sizeof(float2);   // 8 MiB
    if (d_ws != nullptr && ws_size >= ws_needed) {
        float2* S = (float2*)d_ws;
        alpha_k1_states<<<dim3(kChains / kTh), dim3(kTh), 0, stream>>>(in, tau, S);
        alpha_k2_rescan<<<dim3(kB * (kK / 32)), dim3(1024), 0, stream>>>(
            in, il, tau, S, out);
    } else {
        // Fallback: verified single-kernel chunked scan (round-3 kernel).
        alpha_scan_c32<<<dim3(kB * (kK / 32)), dim3(1024), 0, stream>>>(
            in, il, tau, out);
    }
}